// Round 14
// baseline (2324.783 us; speedup 1.0000x reference)
//
#include <hip/hip_runtime.h>
#include <hip/hip_bf16.h>

typedef __attribute__((ext_vector_type(8))) short short8;
typedef __attribute__((ext_vector_type(4))) short short4v;
typedef __attribute__((ext_vector_type(4))) float floatx4;

#define B_SZ 2
#define S_SZ 2048
#define HS_SZ 4096
#define NH_SZ 32
#define HD_SZ 128
#define INTER_SZ 11008
#define M_TOT 4096
#define QKV_N 12288
#define GU_N 22016

__device__ __forceinline__ float b2f(short s){
  unsigned int u = ((unsigned int)(unsigned short)s) << 16;
  return __builtin_bit_cast(float, u);
}
__device__ __forceinline__ short f2b(float f){
  unsigned int u = __builtin_bit_cast(unsigned int, f);
  u = (u + 0x7FFFu + ((u >> 16) & 1u)) >> 16;
  return (short)u;
}

typedef __attribute__((address_space(1))) const unsigned int gu32;
typedef __attribute__((address_space(3))) unsigned int lu32;
__device__ __forceinline__ void gl2lds16(const short* g, short* l){
  __builtin_amdgcn_global_load_lds((gu32*)g, (lu32*)l, 16, 0, 0);
}

#define BARRIER() asm volatile("s_barrier" ::: "memory")
#define WAITV4()  asm volatile("s_waitcnt vmcnt(4)" ::: "memory")
#define WAITV2()  asm volatile("s_waitcnt vmcnt(2)" ::: "memory")
#define WAITV0()  asm volatile("s_waitcnt vmcnt(0)" ::: "memory")

// ---------------- f32 -> bf16 convert (weights) ----------------
__global__ void cvt_bf16_kernel(const float* __restrict__ src, short* __restrict__ dst, long n8){
  long idx = (long)blockIdx.x * blockDim.x + threadIdx.x;
  if (idx >= n8) return;
  long e = idx * 8;
  floatx4 v0 = *(const floatx4*)(src + e);
  floatx4 v1 = *(const floatx4*)(src + e + 4);
  short8 o;
  o[0]=f2b(v0[0]); o[1]=f2b(v0[1]); o[2]=f2b(v0[2]); o[3]=f2b(v0[3]);
  o[4]=f2b(v1[0]); o[5]=f2b(v1[1]); o[6]=f2b(v1[2]); o[7]=f2b(v1[3]);
  *(short8*)(dst + e) = o;
}

// ---------------- q/k/v fused convert into one contiguous [12288,4096] bf16 ----------------
__global__ void cvt_qkv_kernel(const float* __restrict__ q, const float* __restrict__ k,
                               const float* __restrict__ v, short* __restrict__ dst){
  const long n8per = (long)HS_SZ*HS_SZ/8;
  long idx = (long)blockIdx.x * blockDim.x + threadIdx.x;
  if (idx >= 3*n8per) return;
  const float* src = (idx < n8per) ? q : (idx < 2*n8per ? k : v);
  long e = (idx < n8per ? idx : (idx < 2*n8per ? idx - n8per : idx - 2*n8per)) * 8;
  floatx4 v0 = *(const floatx4*)(src + e);
  floatx4 v1 = *(const floatx4*)(src + e + 4);
  short8 o;
  o[0]=f2b(v0[0]); o[1]=f2b(v0[1]); o[2]=f2b(v0[2]); o[3]=f2b(v0[3]);
  o[4]=f2b(v1[0]); o[5]=f2b(v1[1]); o[6]=f2b(v1[2]); o[7]=f2b(v1[3]);
  *(short8*)(dst + idx*8) = o;
}

// ---------------- gate/up 16-row-interleaved convert ----------------
__global__ void cvt_gu_kernel(const float* __restrict__ g, const float* __restrict__ u,
                              short* __restrict__ dst){
  long idx = (long)blockIdx.x * blockDim.x + threadIdx.x;
  const long n8 = (long)INTER_SZ * HS_SZ / 8;
  if (idx >= n8) return;
  long e = idx * 8;
  long row = e / HS_SZ;
  long c = e - row*HS_SZ;
  long drow_g = 32*(row >> 4) + (row & 15);
  {
    floatx4 v0 = *(const floatx4*)(g + e);
    floatx4 v1 = *(const floatx4*)(g + e + 4);
    short8 o;
    o[0]=f2b(v0[0]); o[1]=f2b(v0[1]); o[2]=f2b(v0[2]); o[3]=f2b(v0[3]);
    o[4]=f2b(v1[0]); o[5]=f2b(v1[1]); o[6]=f2b(v1[2]); o[7]=f2b(v1[3]);
    *(short8*)(dst + drow_g*HS_SZ + c) = o;
  }
  {
    floatx4 v0 = *(const floatx4*)(u + e);
    floatx4 v1 = *(const floatx4*)(u + e + 4);
    short8 o;
    o[0]=f2b(v0[0]); o[1]=f2b(v0[1]); o[2]=f2b(v0[2]); o[3]=f2b(v0[3]);
    o[4]=f2b(v1[0]); o[5]=f2b(v1[1]); o[6]=f2b(v1[2]); o[7]=f2b(v1[3]);
    *(short8*)(dst + (drow_g + 16)*HS_SZ + c) = o;
  }
}

// ---------------- embedding gather + concat -> X0 bf16 [M, 2*HS] ----------------
__global__ void embed_concat_kernel(const float* __restrict__ hidden,
                                    const int* __restrict__ ids,
                                    const float* __restrict__ embed,
                                    short* __restrict__ X0){
  long idx = (long)blockIdx.x * blockDim.x + threadIdx.x;
  const long total = (long)M_TOT * (2*HS_SZ) / 4;
  if (idx >= total) return;
  long e = idx * 4;
  int m = (int)(e / (2*HS_SZ));
  int c = (int)(e % (2*HS_SZ));
  const float* src;
  if (c < HS_SZ){
    src = embed + (long)ids[m]*HS_SZ + c;
  } else {
    src = hidden + (long)m*HS_SZ + (c - HS_SZ);
  }
  floatx4 v = *(const floatx4*)src;
  short4v o;
  o[0]=f2b(v[0]); o[1]=f2b(v[1]); o[2]=f2b(v[2]); o[3]=f2b(v[3]);
  *(short4v*)(X0 + e) = o;
}

// ---------------- 256x256 NT GEMM, 6-barrier 3-phase schedule ----------------
// C[M,N](ldc) = A(bf16,[M,K],lda) * B(bf16,[N,K])^T, B rows >= nsplit from Bw2.
// Phases: P1{LD A0,B0; stage A0'; MMQ(0,0); w4}  P2{LD B1; stage B0'; MMQ(0,1); w4}
//         P3{LD A1; stage B1',A1'; MMQ(1,1)+MMQ(1,0); w4}.
// FIFO invariant: entering each tile, in-flight = {B1,A1} = 4 loads.
// P1's w4 drains B1 (needed P2); P2's w4 drains A1 (needed P3); P3's w4 drains
// A0',B0' (needed next P1).  Tail: w2 / w0 / none.
// EPI 0: bf16.  1: +bias -> bf16.  2: +resid(bf16) -> bf16.  3: +resid(bf16) -> f32.
// EPI 4: 16-row-interleaved gate/up -> act = silu(g)*u bf16 [M, ldc].
#define G_STAGE(op,h,kof,qb) { \
  gl2lds16(gs[op][h] + (kof), lds + (qb) + (op)*16384 + (h)*8192 + wid*1024); \
  gl2lds16(gs[op][h] + k8o[op] + (kof), lds + (qb) + (op)*16384 + (h)*8192 + wid*1024 + 512); }

#define LD_A(Mh,pb) { \
  _Pragma("unroll") \
  for (int mf=0; mf<4; mf++) \
    _Pragma("unroll") \
    for (int ks=0; ks<2; ks++) \
      af[mf][ks] = *(const short8*)(lds + (pb) + ((Mh)*128 + wr2*64 + mf*16 + lr)*64 + (((ks*4+lk)^lr7))*8); }

#define LD_B(BB,Nh,pb) { \
  _Pragma("unroll") \
  for (int nf=0; nf<2; nf++) \
    _Pragma("unroll") \
    for (int ks=0; ks<2; ks++) \
      BB[nf][ks] = *(const short8*)(lds + (pb) + 16384 + ((Nh)*128 + wc2*32 + nf*16 + lr)*64 + (((ks*4+lk)^lr7))*8); }

#define MMQ(Mh,Nh,BB) { \
  __builtin_amdgcn_s_setprio(1); \
  _Pragma("unroll") \
  for (int mf=0; mf<4; mf++) \
    _Pragma("unroll") \
    for (int nf=0; nf<2; nf++){ \
      acc[Mh][Nh][mf][nf] = __builtin_amdgcn_mfma_f32_16x16x32_bf16(af[mf][0], BB[nf][0], acc[Mh][Nh][mf][nf], 0,0,0); \
      acc[Mh][Nh][mf][nf] = __builtin_amdgcn_mfma_f32_16x16x32_bf16(af[mf][1], BB[nf][1], acc[Mh][Nh][mf][nf], 0,0,0); \
    } \
  __builtin_amdgcn_s_setprio(0); }

template<int EPI>
__global__ __launch_bounds__(512, 2)
void gemm256_kernel(const short* __restrict__ A, const short* __restrict__ Bw,
                    const short* __restrict__ Bw2, int nsplit,
                    int K, int lda, int ldc,
                    const float* __restrict__ bias,
                    const short* __restrict__ residb,
                    short* __restrict__ Cbf,
                    float* __restrict__ Cf){
  __shared__ __align__(16) short lds[65536];
  const int tid = threadIdx.x;
  const int wid = tid >> 6;
  const int lane = tid & 63;
  const int wr2 = wid >> 2, wc2 = wid & 3;
  const int lr = lane & 15, lk = lane >> 4;
  const int lr7 = lr & 7;

  const int nwg = gridDim.x * gridDim.y;
  const int id  = blockIdx.y * gridDim.x + blockIdx.x;
  const int cpx = nwg >> 3;
  const int sw  = (id & 7) * cpx + (id >> 3);
  const int bx  = sw % gridDim.x;
  const int by  = sw / gridDim.x;
  const int m0 = bx * 256, n0 = by * 256;

  const int srow = lane >> 3;
  const int sslot = (lane & 7) ^ srow;
  const long k8o[2] = { 8L * lda, 8L * K };
  const short* gs[2][2];
  #pragma unroll
  for (int h=0; h<2; h++){
    const int rowa = m0 + h*128 + wid*16 + srow;
    gs[0][h] = A + (long)rowa*lda + sslot*8;
    const int rowb = n0 + h*128 + wid*16 + srow;
    gs[1][h] = (rowb < nsplit ? Bw + (long)rowb*K
                              : Bw2 + (long)(rowb - nsplit)*K) + sslot*8;
  }

  floatx4 acc[2][2][4][2] = {};
  short8 af[4][2], b0[2][2], b1[2][2];
  const int nt = K >> 6;

  // prologue: tile 0 -> buf 0 (8 loads); WAITV4 leaves {B1,A1}=4 in flight.
  G_STAGE(0,0,0,0); G_STAGE(1,0,0,0); G_STAGE(1,1,0,0); G_STAGE(0,1,0,0);
  WAITV4(); BARRIER();

  for (int t = 0; t < nt; ++t){
    const int pb = (t & 1) << 15;
    const int qb = pb ^ 32768;
    const bool nx = (t + 1 < nt);
    const long kof = (long)(t+1) * 64;
    // P1
    LD_A(0,pb); LD_B(b0,0,pb);
    if (nx) G_STAGE(0,0,kof,qb);
    BARRIER();
    MMQ(0,0,b0);
    if (nx) { WAITV4(); } else { WAITV2(); }
    BARRIER();
    // P2
    LD_B(b1,1,pb);
    if (nx) G_STAGE(1,0,kof,qb);
    BARRIER();
    MMQ(0,1,b1);
    if (nx) { WAITV4(); } else { WAITV0(); }
    BARRIER();
    // P3 (merged)
    LD_A(1,pb);
    if (nx) { G_STAGE(1,1,kof,qb); G_STAGE(0,1,kof,qb); }
    BARRIER();
    MMQ(1,1,b1);
    MMQ(1,0,b0);
    if (nx) { WAITV4(); }
    BARRIER();
  }

  if (EPI==4){
    #pragma unroll
    for (int Mh=0; Mh<2; Mh++){
      #pragma unroll
      for (int Nh=0; Nh<2; Nh++){
        const int col = (n0>>1) + Nh*64 + wc2*16 + lr;
        #pragma unroll
        for (int mf=0; mf<4; mf++){
          #pragma unroll
          for (int r=0; r<4; r++){
            const int row = m0 + Mh*128 + wr2*64 + mf*16 + lk*4 + r;
            float g = acc[Mh][Nh][mf][0][r];
            float u = acc[Mh][Nh][mf][1][r];
            float s = g / (1.0f + __expf(-g));
            Cbf[(long)row*ldc + col] = f2b(s*u);
          }
        }
      }
    }
  } else {
    #pragma unroll
    for (int Mh=0; Mh<2; Mh++){
      #pragma unroll
      for (int Nh=0; Nh<2; Nh++){
        #pragma unroll
        for (int mf=0; mf<4; mf++){
          #pragma unroll
          for (int nf=0; nf<2; nf++){
            const int col = n0 + Nh*128 + wc2*32 + nf*16 + lr;
            float bcol = (EPI==1) ? bias[col] : 0.0f;
            #pragma unroll
            for (int r=0; r<4; r++){
              const int row = m0 + Mh*128 + wr2*64 + mf*16 + lk*4 + r;
              float v = acc[Mh][Nh][mf][nf][r] + bcol;
              if (EPI==2 || EPI==3) v += b2f(residb[(long)row*ldc + col]);
              if (EPI==3) Cf[(long)row*ldc + col] = v;
              else        Cbf[(long)row*ldc + col] = f2b(v);
            }
          }
        }
      }
    }
  }
}

// ---------------- RoPE in-place on q,k inside qkv_bf [M, 12288], 4 pairs/thread ----------------
__global__ void rope_kernel(short* __restrict__ qkv, const int* __restrict__ pos_ids){
  long idx = (long)blockIdx.x * blockDim.x + threadIdx.x;
  const long total = (long)M_TOT * NH_SZ * 16;
  if (idx >= total) return;
  int i4 = (int)(idx & 15);
  long rh = idx >> 4;
  int h  = (int)(rh & 31);
  int m  = (int)(rh >> 5);
  int s  = m & (S_SZ - 1);
  float p = (float)pos_ids[s];
  const float L2_10000 = 13.28771237954945f;
  short* qp = qkv + (long)m*QKV_N + h*HD_SZ + i4*4;
  short* kp = qp + HS_SZ;
  short4v q1 = *(short4v*)qp, q2 = *(short4v*)(qp+64);
  short4v k1 = *(short4v*)kp, k2 = *(short4v*)(kp+64);
  short4v q1o, q2o, k1o, k2o;
  #pragma unroll
  for (int j=0;j<4;j++){
    int i = i4*4 + j;
    float inv = exp2f(-(2.0f*i/(float)HD_SZ) * L2_10000);
    float sn, cs;
    sincosf(p*inv, &sn, &cs);
    float a1=b2f(q1[j]), a2=b2f(q2[j]);
    q1o[j] = f2b(a1*cs - a2*sn);
    q2o[j] = f2b(a2*cs + a1*sn);
    float b1v=b2f(k1[j]), b2v=b2f(k2[j]);
    k1o[j] = f2b(b1v*cs - b2v*sn);
    k2o[j] = f2b(b2v*cs + b1v*sn);
  }
  *(short4v*)qp = q1o; *(short4v*)(qp+64) = q2o;
  *(short4v*)kp = k1o; *(short4v*)(kp+64) = k2o;
}

// ---------------- V transpose: qkv_bf v-part -> VT [B*NH*HD, S] ----------------
__global__ __launch_bounds__(256)
void vtrans_kernel(const short* __restrict__ QKV, short* __restrict__ VT){
  __shared__ short tile[64][68];
  const int s0 = blockIdx.x * 64;
  const int d0 = blockIdx.y * 64;
  const int bh = blockIdx.z;
  const int b = bh >> 5, h = bh & 31;
  const int tid = threadIdx.x;
  #pragma unroll
  for (int it=0; it<2; it++){
    int e = (it*256 + tid) * 8;
    int ss = e >> 6, col = e & 63;
    short8 v = *(const short8*)(QKV + ((long)(b*S_SZ + s0 + ss))*QKV_N + 2*HS_SZ + h*HD_SZ + d0 + col);
    #pragma unroll
    for (int j=0;j<8;j++) tile[ss][col+j] = v[j];
  }
  __syncthreads();
  #pragma unroll
  for (int it=0; it<2; it++){
    int e = (it*256 + tid) * 8;
    int dd = e >> 6, scol = e & 63;
    short8 w;
    #pragma unroll
    for (int j=0;j<8;j++) w[j] = tile[scol+j][dd];
    *(short8*)(VT + ((long)(bh*HD_SZ + d0 + dd))*S_SZ + s0 + scol) = w;
  }
}

// ---------------- causal flash attention: QB=128, 8 waves, KVB=64 dbuf ----------------
__global__ __launch_bounds__(512,1)
void attn_kernel(const short* __restrict__ QKV, const short* __restrict__ VT,
                 short* __restrict__ O){
  constexpr int LPD = 72;
  __shared__ __align__(16) short lds[32768];
  __shared__ __align__(16) short p_lds[8][16*LPD];
  const int bh = blockIdx.y;
  const int b = bh >> 5, h = bh & 31;
  const int qblk = blockIdx.x * 128;
  const int tid = threadIdx.x, wid = tid>>6, lane = tid&63;
  const int lr = lane & 15, lk = lane >> 4;
  const float scale = 0.08838834764831845f;

  const short* qbase = QKV + ((long)(b*S_SZ + qblk + wid*16))*QKV_N + h*HD_SZ;
  short8 qf[4];
  #pragma unroll
  for (int t=0;t<4;t++)
    qf[t] = *(const short8*)(qbase + (long)lr*QKV_N + t*32 + lk*8);

  const short* kb[2]; const short* vb[2];
  int kloff[2], vloff[2];
  #pragma unroll
  for (int p=0;p<2;p++){
    const int i = wid*2 + p;
    const int rowk = i*4 + (lane >> 4);
    const int slotk = (lane & 15) ^ (rowk & 15);
    kb[p] = QKV + ((long)(b*S_SZ) + rowk)*QKV_N + HS_SZ + h*HD_SZ + slotk*8;
    kloff[p] = i*512;
    const int dv = i*8 + (lane >> 3);
    const int slotv = (lane & 7) ^ (dv & 7);
    vb[p] = VT + ((long)(bh*HD_SZ + dv))*S_SZ + slotv*8;
    vloff[p] = 8192 + i*512;
  }

  floatx4 oacc[8] = {};
  float m_run[4] = {-1e30f,-1e30f,-1e30f,-1e30f};
  float l_run[4] = {0.f,0.f,0.f,0.f};

  const int nt = 2*(blockIdx.x + 1);

  #pragma unroll
  for (int p=0;p<2;p++){
    gl2lds16(kb[p], lds + kloff[p]);
    gl2lds16(vb[p], lds + vloff[p]);
  }

  for (int t=0; t<nt; ++t){
    const int dbase = (t & 1) * 16384;
    const int nbase = ((t+1) & 1) * 16384;
    if (t+1 < nt){
      const long kkn = (long)(t+1)*64*QKV_N;
      const long vkn = (long)(t+1)*64;
      #pragma unroll
      for (int p=0;p<2;p++){
        gl2lds16(kb[p] + kkn, lds + nbase + kloff[p]);
        gl2lds16(vb[p] + vkn, lds + nbase + vloff[p]);
      }
      WAITV4();
    } else {
      WAITV0();
    }
    BARRIER();
    const int kv0 = t*64;
    floatx4 sfr[4];
    __builtin_amdgcn_s_setprio(1);
    #pragma unroll
    for (int fn=0; fn<4; fn++){
      floatx4 s = {0.f,0.f,0.f,0.f};
      const int row = fn*16 + lr;
      #pragma unroll
      for (int tq=0; tq<4; tq++){
        short8 kf = *(const short8*)(lds + dbase + row*128 + (((tq*4+lk)^lr)&15)*8);
        s = __builtin_amdgcn_mfma_f32_16x16x32_bf16(qf[tq], kf, s, 0,0,0);
      }
      sfr[fn] = s;
    }
    __builtin_amdgcn_s_setprio(0);
    float pv[4][4];
    #pragma unroll
    for (int fn=0; fn<4; fn++){
      const int col = kv0 + fn*16 + lr;
      #pragma unroll
      for (int r=0;r<4;r++){
        const int row = qblk + wid*16 + lk*4 + r;
        float sv = sfr[fn][r] * scale;
        pv[fn][r] = (col > row) ? -1e30f : sv;
      }
    }
    float mr4[4];
    int small = 1;
    #pragma unroll
    for (int r=0;r<4;r++){
      float mr = fmaxf(fmaxf(pv[0][r], pv[1][r]), fmaxf(pv[2][r], pv[3][r]));
      mr = fmaxf(mr, __shfl_xor(mr, 1, 16));
      mr = fmaxf(mr, __shfl_xor(mr, 2, 16));
      mr = fmaxf(mr, __shfl_xor(mr, 4, 16));
      mr = fmaxf(mr, __shfl_xor(mr, 8, 16));
      mr4[r] = mr;
      small &= (mr <= m_run[r] + 8.0f) ? 1 : 0;
    }
    const int skip = __all(small);
    float alpha_[4];
    #pragma unroll
    for (int r=0;r<4;r++){
      float mnew = skip ? m_run[r] : fmaxf(m_run[r], mr4[r]);
      alpha_[r] = skip ? 1.0f : __expf(m_run[r] - mnew);
      m_run[r] = mnew;
      float rs = 0.f;
      #pragma unroll
      for (int fn=0; fn<4; fn++){
        float e = __expf(pv[fn][r] - mnew);
        p_lds[wid][(lk*4+r)*LPD + fn*16 + lr] = f2b(e);
        rs += e;
      }
      rs += __shfl_xor(rs, 1, 16);
      rs += __shfl_xor(rs, 2, 16);
      rs += __shfl_xor(rs, 4, 16);
      rs += __shfl_xor(rs, 8, 16);
      l_run[r] = l_run[r]*alpha_[r] + rs;
    }
    if (!skip){
      #pragma unroll
      for (int f=0; f<8; f++){
        #pragma unroll
        for (int r=0;r<4;r++) oacc[f][r] *= alpha_[r];
      }
    }
    short8 pf[2];
    #pragma unroll
    for (int tp=0; tp<2; tp++)
      pf[tp] = *(const short8*)(&p_lds[wid][lr*LPD + tp*32 + lk*8]);
    __builtin_amdgcn_s_setprio(1);
    #pragma unroll
    for (int f=0; f<8; f++){
      const int vrow = f*16 + lr;
      #pragma unroll
      for (int tp=0; tp<2; tp++){
        short8 vf = *(const short8*)(lds + dbase + 8192 + vrow*64 + (((tp*4+lk)^(lr&7))&7)*8);
        oacc[f] = __builtin_amdgcn_mfma_f32_16x16x32_bf16(pf[tp], vf, oacc[f], 0,0,0);
      }
    }
    __builtin_amdgcn_s_setprio(0);
    BARRIER();
  }
  #pragma unroll
  for (int r=0;r<4;r++){
    const float inv = 1.0f / l_run[r];
    const long row = (long)(b*S_SZ + qblk + wid*16 + lk*4 + r);
    #pragma unroll
    for (int f=0; f<8; f++){
      O[row*HS_SZ + h*HD_SZ + f*16 + lr] = f2b(oacc[f][r]*inv);
    }
  }
}

// ---------------- RMSNorm: bf16 in -> bf16 out ----------------
__global__ void rmsnorm_kernel(const short* __restrict__ X, const float* __restrict__ W,
                               short* __restrict__ Y){
  const int row = blockIdx.x;
  const short* x = X + (long)row*HS_SZ;
  float ss = 0.f;
  for (int c = threadIdx.x*8; c < HS_SZ; c += 256*8){
    short8 v = *(const short8*)(x + c);
    #pragma unroll
    for (int j=0;j<8;j++){ float f = b2f(v[j]); ss += f*f; }
  }
  ss += __shfl_xor(ss, 32); ss += __shfl_xor(ss, 16);
  ss += __shfl_xor(ss, 8);  ss += __shfl_xor(ss, 4);
  ss += __shfl_xor(ss, 2);  ss += __shfl_xor(ss, 1);
  __shared__ float red[4];
  if ((threadIdx.x & 63) == 0) red[threadIdx.x >> 6] = ss;
  __syncthreads();
  ss = red[0] + red[1] + red[2] + red[3];
  const float rs = rsqrtf(ss / (float)HS_SZ + 1e-6f);
  for (int c = threadIdx.x*8; c < HS_SZ; c += 256*8){
    short8 v = *(const short8*)(x + c);
    floatx4 w0 = *(const floatx4*)(W + c);
    floatx4 w1 = *(const floatx4*)(W + c + 4);
    short8 o;
    #pragma unroll
    for (int j=0;j<4;j++) o[j]   = f2b(b2f(v[j])  *rs*w0[j]);
    #pragma unroll
    for (int j=0;j<4;j++) o[4+j] = f2b(b2f(v[4+j])*rs*w1[j]);
    *(short8*)(Y + (long)row*HS_SZ + c) = o;
  }
}

extern "C" void kernel_launch(void* const* d_in, const int* in_sizes, int n_in,
                              void* d_out, int out_size, void* d_ws, size_t ws_size,
                              hipStream_t stream){
  (void)in_sizes; (void)n_in; (void)out_size;
  const float* hidden = (const float*)d_in[0];
  const int*   ids    = (const int*)d_in[1];
  const int*   pos    = (const int*)d_in[2];
  const float* embed  = (const float*)d_in[3];
  const float* fc_w   = (const float*)d_in[4];
  const float* fc_b   = (const float*)d_in[5];
  const float* q_w    = (const float*)d_in[6];
  const float* k_w    = (const float*)d_in[7];
  const float* v_w    = (const float*)d_in[8];
  const float* o_w    = (const float*)d_in[9];
  const float* gate_w = (const float*)d_in[10];
  const float* up_w   = (const float*)d_in[11];
  const float* down_w = (const float*)d_in[12];
  const float* ln_w   = (const float*)d_in[13];

  char* ws = (char*)d_ws;
  size_t off = 0;
  auto alloc = [&](size_t bytes)->char*{
    char* p = ws + off;
    off = (off + bytes + 255) & ~(size_t)255;
    return p;
  };
  short* wbf   = (short*)alloc((size_t)INTER_SZ*HS_SZ*2);
  short* wgu   = (short*)alloc((size_t)GU_N*HS_SZ*2);
  short* X0    = (short*)alloc((size_t)M_TOT*2*HS_SZ*2);
  short* h_bf  = (short*)alloc((size_t)M_TOT*HS_SZ*2);
  short* qkv_bf= (short*)alloc((size_t)M_TOT*QKV_N*2);
  short* vt_bf = (short*)alloc((size_t)M_TOT*HS_SZ*2);
  short* a_bf  = (short*)alloc((size_t)M_TOT*HS_SZ*2);
  short* h2_bf = (short*)alloc((size_t)M_TOT*HS_SZ*2);
  short* hn_bf = (short*)alloc((size_t)M_TOT*HS_SZ*2);
  if (ws_size < off) return;

  short* wqkv = wgu;        // qkv weights staged at wgu base (dead until gate/up cvt)
  short* act  = qkv_bf;     // silu(g)*u activation [M, 11008] (qkv dead after attn)

  auto cvt = [&](const float* src, short* dst, long n){
    long n8 = n / 8;
    cvt_bf16_kernel<<<(int)((n8 + 255)/256), 256, 0, stream>>>(src, dst, n8);
  };

  embed_concat_kernel<<<32768, 256, 0, stream>>>(hidden, ids, embed, X0);

  // FC: [M,8192] x [4096,8192]^T + bias -> h_bf
  cvt(fc_w, wbf, (long)HS_SZ*2*HS_SZ);
  gemm256_kernel<1><<<dim3(16,16), 512, 0, stream>>>(X0, wbf, nullptr, 1<<30,
                                                     2*HS_SZ, 2*HS_SZ, HS_SZ,
                                                     fc_b, nullptr, h_bf, nullptr);
  // QKV fused (single cvt launch)
  cvt_qkv_kernel<<<(int)((3L*HS_SZ*HS_SZ/8 + 255)/256), 256, 0, stream>>>(q_w, k_w, v_w, wqkv);
  gemm256_kernel<0><<<dim3(16,48), 512, 0, stream>>>(h_bf, wqkv, nullptr, 1<<30,
                                                     HS_SZ, HS_SZ, QKV_N,
                                                     nullptr, nullptr, qkv_bf, nullptr);
  rope_kernel<<<8192, 256, 0, stream>>>(qkv_bf, pos);
  vtrans_kernel<<<dim3(S_SZ/64, HD_SZ/64, B_SZ*NH_SZ), 256, 0, stream>>>(qkv_bf, vt_bf);
  attn_kernel<<<dim3(S_SZ/128, B_SZ*NH_SZ), 512, 0, stream>>>(qkv_bf, vt_bf, a_bf);
  // O-proj + residual(h_bf) -> h2_bf
  cvt(o_w, wbf, (long)HS_SZ*HS_SZ);
  gemm256_kernel<2><<<dim3(16,16), 512, 0, stream>>>(a_bf, wbf, nullptr, 1<<30,
                                                     HS_SZ, HS_SZ, HS_SZ,
                                                     nullptr, h_bf, h2_bf, nullptr);
  rmsnorm_kernel<<<M_TOT, 256, 0, stream>>>(h2_bf, ln_w, hn_bf);
  // gate+up fused with zero-shuffle silu epilogue (16-row interleaved weights)
  cvt_gu_kernel<<<22016, 256, 0, stream>>>(gate_w, up_w, wgu);
  gemm256_kernel<4><<<dim3(16,86), 512, 0, stream>>>(hn_bf, wgu, nullptr, 1<<30,
                                                     HS_SZ, HS_SZ, INTER_SZ,
                                                     nullptr, nullptr, act, nullptr);
  // down + residual(h2_bf) -> d_out (f32)
  cvt(down_w, wbf, (long)HS_SZ*INTER_SZ);
  gemm256_kernel<3><<<dim3(16,16), 512, 0, stream>>>(act, wbf, nullptr, 1<<30,
                                                     INTER_SZ, INTER_SZ, HS_SZ,
                                                     nullptr, h2_bf, nullptr, (float*)d_out);
}

// Round 15
// 2204.741 us; speedup vs baseline: 1.0544x; 1.0544x over previous
//
#include <hip/hip_runtime.h>
#include <hip/hip_bf16.h>

typedef __attribute__((ext_vector_type(8))) short short8;
typedef __attribute__((ext_vector_type(4))) short short4v;
typedef __attribute__((ext_vector_type(4))) float floatx4;

#define B_SZ 2
#define S_SZ 2048
#define HS_SZ 4096
#define NH_SZ 32
#define HD_SZ 128
#define INTER_SZ 11008
#define M_TOT 4096
#define QKV_N 12288
#define GU_N 22016

__device__ __forceinline__ float b2f(short s){
  unsigned int u = ((unsigned int)(unsigned short)s) << 16;
  return __builtin_bit_cast(float, u);
}
__device__ __forceinline__ short f2b(float f){
  unsigned int u = __builtin_bit_cast(unsigned int, f);
  u = (u + 0x7FFFu + ((u >> 16) & 1u)) >> 16;
  return (short)u;
}

typedef __attribute__((address_space(1))) const unsigned int gu32;
typedef __attribute__((address_space(3))) unsigned int lu32;
__device__ __forceinline__ void gl2lds16(const short* g, short* l){
  __builtin_amdgcn_global_load_lds((gu32*)g, (lu32*)l, 16, 0, 0);
}

#define BARRIER() asm volatile("s_barrier" ::: "memory")
#define WAITV4()  asm volatile("s_waitcnt vmcnt(4)" ::: "memory")
#define WAITV2()  asm volatile("s_waitcnt vmcnt(2)" ::: "memory")
#define WAITV0()  asm volatile("s_waitcnt vmcnt(0)" ::: "memory")

// ---------------- f32 -> bf16 convert (weights) ----------------
__global__ void cvt_bf16_kernel(const float* __restrict__ src, short* __restrict__ dst, long n8){
  long idx = (long)blockIdx.x * blockDim.x + threadIdx.x;
  if (idx >= n8) return;
  long e = idx * 8;
  floatx4 v0 = *(const floatx4*)(src + e);
  floatx4 v1 = *(const floatx4*)(src + e + 4);
  short8 o;
  o[0]=f2b(v0[0]); o[1]=f2b(v0[1]); o[2]=f2b(v0[2]); o[3]=f2b(v0[3]);
  o[4]=f2b(v1[0]); o[5]=f2b(v1[1]); o[6]=f2b(v1[2]); o[7]=f2b(v1[3]);
  *(short8*)(dst + e) = o;
}

// ---------------- q/k/v fused convert into one contiguous [12288,4096] bf16 ----------------
__global__ void cvt_qkv_kernel(const float* __restrict__ q, const float* __restrict__ k,
                               const float* __restrict__ v, short* __restrict__ dst){
  const long n8per = (long)HS_SZ*HS_SZ/8;
  long idx = (long)blockIdx.x * blockDim.x + threadIdx.x;
  if (idx >= 3*n8per) return;
  const float* src = (idx < n8per) ? q : (idx < 2*n8per ? k : v);
  long e = (idx < n8per ? idx : (idx < 2*n8per ? idx - n8per : idx - 2*n8per)) * 8;
  floatx4 v0 = *(const floatx4*)(src + e);
  floatx4 v1 = *(const floatx4*)(src + e + 4);
  short8 o;
  o[0]=f2b(v0[0]); o[1]=f2b(v0[1]); o[2]=f2b(v0[2]); o[3]=f2b(v0[3]);
  o[4]=f2b(v1[0]); o[5]=f2b(v1[1]); o[6]=f2b(v1[2]); o[7]=f2b(v1[3]);
  *(short8*)(dst + idx*8) = o;
}

// ---------------- gate/up 16-row-interleaved convert ----------------
__global__ void cvt_gu_kernel(const float* __restrict__ g, const float* __restrict__ u,
                              short* __restrict__ dst){
  long idx = (long)blockIdx.x * blockDim.x + threadIdx.x;
  const long n8 = (long)INTER_SZ * HS_SZ / 8;
  if (idx >= n8) return;
  long e = idx * 8;
  long row = e / HS_SZ;
  long c = e - row*HS_SZ;
  long drow_g = 32*(row >> 4) + (row & 15);
  {
    floatx4 v0 = *(const floatx4*)(g + e);
    floatx4 v1 = *(const floatx4*)(g + e + 4);
    short8 o;
    o[0]=f2b(v0[0]); o[1]=f2b(v0[1]); o[2]=f2b(v0[2]); o[3]=f2b(v0[3]);
    o[4]=f2b(v1[0]); o[5]=f2b(v1[1]); o[6]=f2b(v1[2]); o[7]=f2b(v1[3]);
    *(short8*)(dst + drow_g*HS_SZ + c) = o;
  }
  {
    floatx4 v0 = *(const floatx4*)(u + e);
    floatx4 v1 = *(const floatx4*)(u + e + 4);
    short8 o;
    o[0]=f2b(v0[0]); o[1]=f2b(v0[1]); o[2]=f2b(v0[2]); o[3]=f2b(v0[3]);
    o[4]=f2b(v1[0]); o[5]=f2b(v1[1]); o[6]=f2b(v1[2]); o[7]=f2b(v1[3]);
    *(short8*)(dst + (drow_g + 16)*HS_SZ + c) = o;
  }
}

// ---------------- embedding gather + concat -> X0 bf16 [M, 2*HS] ----------------
__global__ void embed_concat_kernel(const float* __restrict__ hidden,
                                    const int* __restrict__ ids,
                                    const float* __restrict__ embed,
                                    short* __restrict__ X0){
  long idx = (long)blockIdx.x * blockDim.x + threadIdx.x;
  const long total = (long)M_TOT * (2*HS_SZ) / 4;
  if (idx >= total) return;
  long e = idx * 4;
  int m = (int)(e / (2*HS_SZ));
  int c = (int)(e % (2*HS_SZ));
  const float* src;
  if (c < HS_SZ){
    src = embed + (long)ids[m]*HS_SZ + c;
  } else {
    src = hidden + (long)m*HS_SZ + (c - HS_SZ);
  }
  floatx4 v = *(const floatx4*)src;
  short4v o;
  o[0]=f2b(v[0]); o[1]=f2b(v[1]); o[2]=f2b(v[2]); o[3]=f2b(v[3]);
  *(short4v*)(X0 + e) = o;
}

// ---------------- 256x256 NT GEMM, 8-phase (R13 frozen schedule) ----------------
// C[M,N](ldc) = A(bf16,[M,K],lda) * B(bf16,[N,K])^T, B rows >= nsplit from Bw2.
// EPI 0: bf16.  1: +bias -> bf16.  2: +resid(bf16) -> bf16.  3: +resid(bf16) -> f32.
// EPI 4: 16-row-interleaved gate/up -> act = silu(g)*u bf16 [M, ldc].
#define G_STAGE(op,h,kof,qb) { \
  gl2lds16(gs[op][h] + (kof), lds + (qb) + (op)*16384 + (h)*8192 + wid*1024); \
  gl2lds16(gs[op][h] + k8o[op] + (kof), lds + (qb) + (op)*16384 + (h)*8192 + wid*1024 + 512); }

#define LD_A(Mh,pb) { \
  _Pragma("unroll") \
  for (int mf=0; mf<4; mf++) \
    _Pragma("unroll") \
    for (int ks=0; ks<2; ks++) \
      af[mf][ks] = *(const short8*)(lds + (pb) + ((Mh)*128 + wr2*64 + mf*16 + lr)*64 + (((ks*4+lk)^lr7))*8); }

#define LD_B(BB,Nh,pb) { \
  _Pragma("unroll") \
  for (int nf=0; nf<2; nf++) \
    _Pragma("unroll") \
    for (int ks=0; ks<2; ks++) \
      BB[nf][ks] = *(const short8*)(lds + (pb) + 16384 + ((Nh)*128 + wc2*32 + nf*16 + lr)*64 + (((ks*4+lk)^lr7))*8); }

#define MMQ(Mh,Nh,BB) { \
  __builtin_amdgcn_s_setprio(1); \
  _Pragma("unroll") \
  for (int mf=0; mf<4; mf++) \
    _Pragma("unroll") \
    for (int nf=0; nf<2; nf++){ \
      acc[Mh][Nh][mf][nf] = __builtin_amdgcn_mfma_f32_16x16x32_bf16(af[mf][0], BB[nf][0], acc[Mh][Nh][mf][nf], 0,0,0); \
      acc[Mh][Nh][mf][nf] = __builtin_amdgcn_mfma_f32_16x16x32_bf16(af[mf][1], BB[nf][1], acc[Mh][Nh][mf][nf], 0,0,0); \
    } \
  __builtin_amdgcn_s_setprio(0); }

template<int EPI>
__global__ __launch_bounds__(512, 2)
void gemm256_kernel(const short* __restrict__ A, const short* __restrict__ Bw,
                    const short* __restrict__ Bw2, int nsplit,
                    int K, int lda, int ldc,
                    const float* __restrict__ bias,
                    const short* __restrict__ residb,
                    short* __restrict__ Cbf,
                    float* __restrict__ Cf){
  __shared__ __align__(16) short lds[65536];
  const int tid = threadIdx.x;
  const int wid = tid >> 6;
  const int lane = tid & 63;
  const int wr2 = wid >> 2, wc2 = wid & 3;
  const int lr = lane & 15, lk = lane >> 4;
  const int lr7 = lr & 7;

  const int nwg = gridDim.x * gridDim.y;
  const int id  = blockIdx.y * gridDim.x + blockIdx.x;
  const int cpx = nwg >> 3;
  const int sw  = (id & 7) * cpx + (id >> 3);
  const int bx  = sw % gridDim.x;
  const int by  = sw / gridDim.x;
  const int m0 = bx * 256, n0 = by * 256;

  const int srow = lane >> 3;
  const int sslot = (lane & 7) ^ srow;
  const long k8o[2] = { 8L * lda, 8L * K };
  const short* gs[2][2];
  #pragma unroll
  for (int h=0; h<2; h++){
    const int rowa = m0 + h*128 + wid*16 + srow;
    gs[0][h] = A + (long)rowa*lda + sslot*8;
    const int rowb = n0 + h*128 + wid*16 + srow;
    gs[1][h] = (rowb < nsplit ? Bw + (long)rowb*K
                              : Bw2 + (long)(rowb - nsplit)*K) + sslot*8;
  }

  floatx4 acc[2][2][4][2] = {};
  short8 af[4][2], b0[2][2], b1[2][2];
  const int nt = K >> 6;

  G_STAGE(0,0,0,0); G_STAGE(1,0,0,0); G_STAGE(1,1,0,0); G_STAGE(0,1,0,0);
  WAITV4(); BARRIER();

  for (int t = 0; t < nt-1; ++t){
    const int pb = (t & 1) << 15;
    const int qb = pb ^ 32768;
    const long kof = (long)(t+1) * 64;
    LD_A(0,pb); LD_B(b0,0,pb);
    G_STAGE(0,0,kof,qb);
    BARRIER();
    MMQ(0,0,b0);
    WAITV4(); BARRIER();
    LD_B(b1,1,pb);
    G_STAGE(1,0,kof,qb);
    BARRIER();
    MMQ(0,1,b1);
    WAITV4(); BARRIER();
    LD_A(1,pb);
    G_STAGE(1,1,kof,qb);
    BARRIER();
    MMQ(1,1,b1);
    BARRIER();
    G_STAGE(0,1,kof,qb);
    BARRIER();
    MMQ(1,0,b0);
    WAITV4(); BARRIER();
  }
  {
    const int pb = ((nt-1) & 1) << 15;
    LD_A(0,pb); LD_B(b0,0,pb);
    BARRIER(); MMQ(0,0,b0);
    WAITV2(); BARRIER();
    LD_B(b1,1,pb);
    BARRIER(); MMQ(0,1,b1);
    WAITV0(); BARRIER();
    LD_A(1,pb);
    BARRIER(); MMQ(1,1,b1);
    BARRIER();
    MMQ(1,0,b0);
  }

  if (EPI==4){
    #pragma unroll
    for (int Mh=0; Mh<2; Mh++){
      #pragma unroll
      for (int Nh=0; Nh<2; Nh++){
        const int col = (n0>>1) + Nh*64 + wc2*16 + lr;
        #pragma unroll
        for (int mf=0; mf<4; mf++){
          #pragma unroll
          for (int r=0; r<4; r++){
            const int row = m0 + Mh*128 + wr2*64 + mf*16 + lk*4 + r;
            float g = acc[Mh][Nh][mf][0][r];
            float u = acc[Mh][Nh][mf][1][r];
            float s = g / (1.0f + __expf(-g));
            Cbf[(long)row*ldc + col] = f2b(s*u);
          }
        }
      }
    }
  } else {
    #pragma unroll
    for (int Mh=0; Mh<2; Mh++){
      #pragma unroll
      for (int Nh=0; Nh<2; Nh++){
        #pragma unroll
        for (int mf=0; mf<4; mf++){
          #pragma unroll
          for (int nf=0; nf<2; nf++){
            const int col = n0 + Nh*128 + wc2*32 + nf*16 + lr;
            float bcol = (EPI==1) ? bias[col] : 0.0f;
            #pragma unroll
            for (int r=0; r<4; r++){
              const int row = m0 + Mh*128 + wr2*64 + mf*16 + lk*4 + r;
              float v = acc[Mh][Nh][mf][nf][r] + bcol;
              if (EPI==2 || EPI==3) v += b2f(residb[(long)row*ldc + col]);
              if (EPI==3) Cf[(long)row*ldc + col] = v;
              else        Cbf[(long)row*ldc + col] = f2b(v);
            }
          }
        }
      }
    }
  }
}

// ---------------- RoPE in-place on q,k inside qkv_bf [M, 12288], 4 pairs/thread ----------------
__global__ void rope_kernel(short* __restrict__ qkv, const int* __restrict__ pos_ids){
  long idx = (long)blockIdx.x * blockDim.x + threadIdx.x;
  const long total = (long)M_TOT * NH_SZ * 16;
  if (idx >= total) return;
  int i4 = (int)(idx & 15);
  long rh = idx >> 4;
  int h  = (int)(rh & 31);
  int m  = (int)(rh >> 5);
  int s  = m & (S_SZ - 1);
  float p = (float)pos_ids[s];
  const float L2_10000 = 13.28771237954945f;
  short* qp = qkv + (long)m*QKV_N + h*HD_SZ + i4*4;
  short* kp = qp + HS_SZ;
  short4v q1 = *(short4v*)qp, q2 = *(short4v*)(qp+64);
  short4v k1 = *(short4v*)kp, k2 = *(short4v*)(kp+64);
  short4v q1o, q2o, k1o, k2o;
  #pragma unroll
  for (int j=0;j<4;j++){
    int i = i4*4 + j;
    float inv = exp2f(-(2.0f*i/(float)HD_SZ) * L2_10000);
    float sn, cs;
    sincosf(p*inv, &sn, &cs);
    float a1=b2f(q1[j]), a2=b2f(q2[j]);
    q1o[j] = f2b(a1*cs - a2*sn);
    q2o[j] = f2b(a2*cs + a1*sn);
    float b1v=b2f(k1[j]), b2v=b2f(k2[j]);
    k1o[j] = f2b(b1v*cs - b2v*sn);
    k2o[j] = f2b(b2v*cs + b1v*sn);
  }
  *(short4v*)qp = q1o; *(short4v*)(qp+64) = q2o;
  *(short4v*)kp = k1o; *(short4v*)(kp+64) = k2o;
}

// ---------------- V transpose: qkv_bf v-part -> VT [B*NH*HD, S] ----------------
__global__ __launch_bounds__(256)
void vtrans_kernel(const short* __restrict__ QKV, short* __restrict__ VT){
  __shared__ short tile[64][68];
  const int s0 = blockIdx.x * 64;
  const int d0 = blockIdx.y * 64;
  const int bh = blockIdx.z;
  const int b = bh >> 5, h = bh & 31;
  const int tid = threadIdx.x;
  #pragma unroll
  for (int it=0; it<2; it++){
    int e = (it*256 + tid) * 8;
    int ss = e >> 6, col = e & 63;
    short8 v = *(const short8*)(QKV + ((long)(b*S_SZ + s0 + ss))*QKV_N + 2*HS_SZ + h*HD_SZ + d0 + col);
    #pragma unroll
    for (int j=0;j<8;j++) tile[ss][col+j] = v[j];
  }
  __syncthreads();
  #pragma unroll
  for (int it=0; it<2; it++){
    int e = (it*256 + tid) * 8;
    int dd = e >> 6, scol = e & 63;
    short8 w;
    #pragma unroll
    for (int j=0;j<8;j++) w[j] = tile[scol+j][dd];
    *(short8*)(VT + ((long)(bh*HD_SZ + d0 + dd))*S_SZ + s0 + scol) = w;
  }
}

// ---------------- causal flash attention: QB=128, 8 waves, KVB=64 dbuf ----------------
__global__ __launch_bounds__(512,1)
void attn_kernel(const short* __restrict__ QKV, const short* __restrict__ VT,
                 short* __restrict__ O){
  constexpr int LPD = 72;
  __shared__ __align__(16) short lds[32768];
  __shared__ __align__(16) short p_lds[8][16*LPD];
  const int bh = blockIdx.y;
  const int b = bh >> 5, h = bh & 31;
  const int qblk = blockIdx.x * 128;
  const int tid = threadIdx.x, wid = tid>>6, lane = tid&63;
  const int lr = lane & 15, lk = lane >> 4;
  const float scale = 0.08838834764831845f;

  const short* qbase = QKV + ((long)(b*S_SZ + qblk + wid*16))*QKV_N + h*HD_SZ;
  short8 qf[4];
  #pragma unroll
  for (int t=0;t<4;t++)
    qf[t] = *(const short8*)(qbase + (long)lr*QKV_N + t*32 + lk*8);

  const short* kb[2]; const short* vb[2];
  int kloff[2], vloff[2];
  #pragma unroll
  for (int p=0;p<2;p++){
    const int i = wid*2 + p;
    const int rowk = i*4 + (lane >> 4);
    const int slotk = (lane & 15) ^ (rowk & 15);
    kb[p] = QKV + ((long)(b*S_SZ) + rowk)*QKV_N + HS_SZ + h*HD_SZ + slotk*8;
    kloff[p] = i*512;
    const int dv = i*8 + (lane >> 3);
    const int slotv = (lane & 7) ^ (dv & 7);
    vb[p] = VT + ((long)(bh*HD_SZ + dv))*S_SZ + slotv*8;
    vloff[p] = 8192 + i*512;
  }

  floatx4 oacc[8] = {};
  float m_run[4] = {-1e30f,-1e30f,-1e30f,-1e30f};
  float l_run[4] = {0.f,0.f,0.f,0.f};

  const int nt = 2*(blockIdx.x + 1);

  #pragma unroll
  for (int p=0;p<2;p++){
    gl2lds16(kb[p], lds + kloff[p]);
    gl2lds16(vb[p], lds + vloff[p]);
  }

  for (int t=0; t<nt; ++t){
    const int dbase = (t & 1) * 16384;
    const int nbase = ((t+1) & 1) * 16384;
    if (t+1 < nt){
      const long kkn = (long)(t+1)*64*QKV_N;
      const long vkn = (long)(t+1)*64;
      #pragma unroll
      for (int p=0;p<2;p++){
        gl2lds16(kb[p] + kkn, lds + nbase + kloff[p]);
        gl2lds16(vb[p] + vkn, lds + nbase + vloff[p]);
      }
      WAITV4();
    } else {
      WAITV0();
    }
    BARRIER();
    const int kv0 = t*64;
    floatx4 sfr[4];
    __builtin_amdgcn_s_setprio(1);
    #pragma unroll
    for (int fn=0; fn<4; fn++){
      floatx4 s = {0.f,0.f,0.f,0.f};
      const int row = fn*16 + lr;
      #pragma unroll
      for (int tq=0; tq<4; tq++){
        short8 kf = *(const short8*)(lds + dbase + row*128 + (((tq*4+lk)^lr)&15)*8);
        s = __builtin_amdgcn_mfma_f32_16x16x32_bf16(qf[tq], kf, s, 0,0,0);
      }
      sfr[fn] = s;
    }
    __builtin_amdgcn_s_setprio(0);
    float pv[4][4];
    #pragma unroll
    for (int fn=0; fn<4; fn++){
      const int col = kv0 + fn*16 + lr;
      #pragma unroll
      for (int r=0;r<4;r++){
        const int row = qblk + wid*16 + lk*4 + r;
        float sv = sfr[fn][r] * scale;
        pv[fn][r] = (col > row) ? -1e30f : sv;
      }
    }
    float mr4[4];
    int small = 1;
    #pragma unroll
    for (int r=0;r<4;r++){
      float mr = fmaxf(fmaxf(pv[0][r], pv[1][r]), fmaxf(pv[2][r], pv[3][r]));
      mr = fmaxf(mr, __shfl_xor(mr, 1, 16));
      mr = fmaxf(mr, __shfl_xor(mr, 2, 16));
      mr = fmaxf(mr, __shfl_xor(mr, 4, 16));
      mr = fmaxf(mr, __shfl_xor(mr, 8, 16));
      mr4[r] = mr;
      small &= (mr <= m_run[r] + 8.0f) ? 1 : 0;
    }
    const int skip = __all(small);
    float alpha_[4];
    #pragma unroll
    for (int r=0;r<4;r++){
      float mnew = skip ? m_run[r] : fmaxf(m_run[r], mr4[r]);
      alpha_[r] = skip ? 1.0f : __expf(m_run[r] - mnew);
      m_run[r] = mnew;
      float rs = 0.f;
      #pragma unroll
      for (int fn=0; fn<4; fn++){
        float e = __expf(pv[fn][r] - mnew);
        p_lds[wid][(lk*4+r)*LPD + fn*16 + lr] = f2b(e);
        rs += e;
      }
      rs += __shfl_xor(rs, 1, 16);
      rs += __shfl_xor(rs, 2, 16);
      rs += __shfl_xor(rs, 4, 16);
      rs += __shfl_xor(rs, 8, 16);
      l_run[r] = l_run[r]*alpha_[r] + rs;
    }
    if (!skip){
      #pragma unroll
      for (int f=0; f<8; f++){
        #pragma unroll
        for (int r=0;r<4;r++) oacc[f][r] *= alpha_[r];
      }
    }
    short8 pf[2];
    #pragma unroll
    for (int tp=0; tp<2; tp++)
      pf[tp] = *(const short8*)(&p_lds[wid][lr*LPD + tp*32 + lk*8]);
    __builtin_amdgcn_s_setprio(1);
    #pragma unroll
    for (int f=0; f<8; f++){
      const int vrow = f*16 + lr;
      #pragma unroll
      for (int tp=0; tp<2; tp++){
        short8 vf = *(const short8*)(lds + dbase + 8192 + vrow*64 + (((tp*4+lk)^(lr&7))&7)*8);
        oacc[f] = __builtin_amdgcn_mfma_f32_16x16x32_bf16(pf[tp], vf, oacc[f], 0,0,0);
      }
    }
    __builtin_amdgcn_s_setprio(0);
    BARRIER();
  }
  #pragma unroll
  for (int r=0;r<4;r++){
    const float inv = 1.0f / l_run[r];
    const long row = (long)(b*S_SZ + qblk + wid*16 + lk*4 + r);
    #pragma unroll
    for (int f=0; f<8; f++){
      O[row*HS_SZ + h*HD_SZ + f*16 + lr] = f2b(oacc[f][r]*inv);
    }
  }
}

// ---------------- RMSNorm: bf16 in -> bf16 out ----------------
__global__ void rmsnorm_kernel(const short* __restrict__ X, const float* __restrict__ W,
                               short* __restrict__ Y){
  const int row = blockIdx.x;
  const short* x = X + (long)row*HS_SZ;
  float ss = 0.f;
  for (int c = threadIdx.x*8; c < HS_SZ; c += 256*8){
    short8 v = *(const short8*)(x + c);
    #pragma unroll
    for (int j=0;j<8;j++){ float f = b2f(v[j]); ss += f*f; }
  }
  ss += __shfl_xor(ss, 32); ss += __shfl_xor(ss, 16);
  ss += __shfl_xor(ss, 8);  ss += __shfl_xor(ss, 4);
  ss += __shfl_xor(ss, 2);  ss += __shfl_xor(ss, 1);
  __shared__ float red[4];
  if ((threadIdx.x & 63) == 0) red[threadIdx.x >> 6] = ss;
  __syncthreads();
  ss = red[0] + red[1] + red[2] + red[3];
  const float rs = rsqrtf(ss / (float)HS_SZ + 1e-6f);
  for (int c = threadIdx.x*8; c < HS_SZ; c += 256*8){
    short8 v = *(const short8*)(x + c);
    floatx4 w0 = *(const floatx4*)(W + c);
    floatx4 w1 = *(const floatx4*)(W + c + 4);
    short8 o;
    #pragma unroll
    for (int j=0;j<4;j++) o[j]   = f2b(b2f(v[j])  *rs*w0[j]);
    #pragma unroll
    for (int j=0;j<4;j++) o[4+j] = f2b(b2f(v[4+j])*rs*w1[j]);
    *(short8*)(Y + (long)row*HS_SZ + c) = o;
  }
}

extern "C" void kernel_launch(void* const* d_in, const int* in_sizes, int n_in,
                              void* d_out, int out_size, void* d_ws, size_t ws_size,
                              hipStream_t stream){
  (void)in_sizes; (void)n_in; (void)out_size;
  const float* hidden = (const float*)d_in[0];
  const int*   ids    = (const int*)d_in[1];
  const int*   pos    = (const int*)d_in[2];
  const float* embed  = (const float*)d_in[3];
  const float* fc_w   = (const float*)d_in[4];
  const float* fc_b   = (const float*)d_in[5];
  const float* q_w    = (const float*)d_in[6];
  const float* k_w    = (const float*)d_in[7];
  const float* v_w    = (const float*)d_in[8];
  const float* o_w    = (const float*)d_in[9];
  const float* gate_w = (const float*)d_in[10];
  const float* up_w   = (const float*)d_in[11];
  const float* down_w = (const float*)d_in[12];
  const float* ln_w   = (const float*)d_in[13];

  char* ws = (char*)d_ws;
  size_t off = 0;
  auto alloc = [&](size_t bytes)->char*{
    char* p = ws + off;
    off = (off + bytes + 255) & ~(size_t)255;
    return p;
  };
  short* wbf   = (short*)alloc((size_t)INTER_SZ*HS_SZ*2);
  short* wgu   = (short*)alloc((size_t)GU_N*HS_SZ*2);
  short* X0    = (short*)alloc((size_t)M_TOT*2*HS_SZ*2);
  short* h_bf  = (short*)alloc((size_t)M_TOT*HS_SZ*2);
  short* qkv_bf= (short*)alloc((size_t)M_TOT*QKV_N*2);
  short* vt_bf = (short*)alloc((size_t)M_TOT*HS_SZ*2);
  short* a_bf  = (short*)alloc((size_t)M_TOT*HS_SZ*2);
  short* h2_bf = (short*)alloc((size_t)M_TOT*HS_SZ*2);
  short* hn_bf = (short*)alloc((size_t)M_TOT*HS_SZ*2);
  if (ws_size < off) return;

  short* wqkv = wgu;        // qkv weights staged at wgu base (dead until gate/up cvt)
  short* act  = qkv_bf;     // silu(g)*u activation [M, 11008] (qkv dead after attn)

  auto cvt = [&](const float* src, short* dst, long n){
    long n8 = n / 8;
    cvt_bf16_kernel<<<(int)((n8 + 255)/256), 256, 0, stream>>>(src, dst, n8);
  };

  embed_concat_kernel<<<32768, 256, 0, stream>>>(hidden, ids, embed, X0);

  // FC: [M,8192] x [4096,8192]^T + bias -> h_bf
  cvt(fc_w, wbf, (long)HS_SZ*2*HS_SZ);
  gemm256_kernel<1><<<dim3(16,16), 512, 0, stream>>>(X0, wbf, nullptr, 1<<30,
                                                     2*HS_SZ, 2*HS_SZ, HS_SZ,
                                                     fc_b, nullptr, h_bf, nullptr);
  // QKV fused (single cvt launch)
  cvt_qkv_kernel<<<(int)((3L*HS_SZ*HS_SZ/8 + 255)/256), 256, 0, stream>>>(q_w, k_w, v_w, wqkv);
  gemm256_kernel<0><<<dim3(16,48), 512, 0, stream>>>(h_bf, wqkv, nullptr, 1<<30,
                                                     HS_SZ, HS_SZ, QKV_N,
                                                     nullptr, nullptr, qkv_bf, nullptr);
  rope_kernel<<<8192, 256, 0, stream>>>(qkv_bf, pos);
  vtrans_kernel<<<dim3(S_SZ/64, HD_SZ/64, B_SZ*NH_SZ), 256, 0, stream>>>(qkv_bf, vt_bf);
  attn_kernel<<<dim3(S_SZ/128, B_SZ*NH_SZ), 512, 0, stream>>>(qkv_bf, vt_bf, a_bf);
  // O-proj + residual(h_bf) -> h2_bf
  cvt(o_w, wbf, (long)HS_SZ*HS_SZ);
  gemm256_kernel<2><<<dim3(16,16), 512, 0, stream>>>(a_bf, wbf, nullptr, 1<<30,
                                                     HS_SZ, HS_SZ, HS_SZ,
                                                     nullptr, h_bf, h2_bf, nullptr);
  rmsnorm_kernel<<<M_TOT, 256, 0, stream>>>(h2_bf, ln_w, hn_bf);
  // gate+up fused with zero-shuffle silu epilogue (16-row interleaved weights)
  cvt_gu_kernel<<<22016, 256, 0, stream>>>(gate_w, up_w, wgu);
  gemm256_kernel<4><<<dim3(16,86), 512, 0, stream>>>(hn_bf, wgu, nullptr, 1<<30,
                                                     HS_SZ, HS_SZ, INTER_SZ,
                                                     nullptr, nullptr, act, nullptr);
  // down + residual(h2_bf) -> d_out (f32)
  cvt(down_w, wbf, (long)HS_SZ*INTER_SZ);
  gemm256_kernel<3><<<dim3(16,16), 512, 0, stream>>>(act, wbf, nullptr, 1<<30,
                                                     INTER_SZ, INTER_SZ, HS_SZ,
                                                     nullptr, h2_bf, nullptr, (float*)d_out);
}